// Round 18
// baseline (152.059 us; speedup 1.0000x reference)
//
#include <hip/hip_runtime.h>

typedef unsigned short ushort_t;
typedef __attribute__((ext_vector_type(8))) short bf16x8;   // 8 bf16 (4 VGPRs) MFMA A/B frag
typedef __attribute__((ext_vector_type(4))) float f32x4;    // 16x16 MFMA C/D frag
typedef __attribute__((ext_vector_type(16))) float f32x16;  // 32x32 MFMA C/D frag
typedef __attribute__((ext_vector_type(4))) unsigned short u16x4;
typedef __attribute__((ext_vector_type(2))) int i32x2;

__device__ __forceinline__ ushort_t f2bf(float f) {
  unsigned int u = __float_as_uint(f);
  u += 0x7FFFu + ((u >> 16) & 1u);   // RNE (inputs finite)
  return (ushort_t)(u >> 16);
}

__device__ __forceinline__ int cvt_pk_bf16(float lo, float hi) {
  int r;
  asm("v_cvt_pk_bf16_f32 %0, %1, %2" : "=v"(r) : "v"(lo), "v"(hi));
  return r;
}

__device__ __forceinline__ void gload16(const void* g, void* l) {
  __builtin_amdgcn_global_load_lds((__attribute__((address_space(1))) void*)g,
                                   (__attribute__((address_space(3))) void*)l, 16, 0, 0);
}

// ---------------- prep: x cast + both weight transposes in ONE launch ----------------

__global__ __launch_bounds__(256) void prep_kernel(
    const float* __restrict__ x, ushort_t* __restrict__ xb,
    const float* __restrict__ w_qkv, ushort_t* __restrict__ Wq,
    const float* __restrict__ w_proj, ushort_t* __restrict__ Wp) {
  const int bx = blockIdx.x;
  const int tid = threadIdx.x;
  if (bx >= 1024) {
    int i = (bx - 1024) * 256 + tid;
    float4 v = ((const float4*)x)[i];
    u16x4 o = {f2bf(v.x), f2bf(v.y), f2bf(v.z), f2bf(v.w)};
    *(u16x4*)(xb + (size_t)i * 4) = o;
    return;
  }
  __shared__ float tile[64][65];
  const int cbx = bx & 63, ry = bx >> 6;
  const float* in = cbx < 48 ? w_qkv : w_proj;
  ushort_t* out = cbx < 48 ? Wq : Wp;
  const int C = cbx < 48 ? 3072 : 1024;
  const int cb = cbx < 48 ? cbx : cbx - 48;
  int c0 = cb * 64, r0 = ry * 64;
  int lr = tid >> 2, q = tid & 3;
  const float* ip = in + (size_t)(r0 + lr) * C + c0 + q * 16;
#pragma unroll
  for (int j = 0; j < 16; ++j) tile[lr][q * 16 + j] = ip[j];
  __syncthreads();
  int oc = tid >> 2;
  ushort_t* op = out + (size_t)(c0 + oc) * 1024 + r0 + q * 16;
#pragma unroll
  for (int j = 0; j < 16; ++j) op[j] = f2bf(tile[q * 16 + j][oc]);
}

// ---------------- GEMM: C[M][N] = A[M][K] * Bt[N][K]^T + bias ----------------
// Template geometry: MODE 0 = 256Mx128N tile, 8 waves (512 thr), 48KB LDS;
//                    MODE 1 = 128Mx128N tile, 4 waves (256 thr), 32KB LDS.
// Both: BK=64, single LDS buffer, drain sync, wave owns 64x64 (acc[4][4]),
// rows 128B = 8 chunks, chunk g stored at g^(row&7), 2D XCD rectangle decode.
// MODE 0: write bf16 Q/K [bh][t][d] and V TRANSPOSED [bh][d][t].
// MODE 1: write fp32 d_out.

template <int MODE>
__global__ __launch_bounds__(MODE == 0 ? 512 : 256, MODE == 0 ? 4 : 4) void gemm_kernel(
    const ushort_t* __restrict__ A, const ushort_t* __restrict__ Bt,
    const float* __restrict__ bias, float* __restrict__ OutF,
    ushort_t* __restrict__ Qh, ushort_t* __restrict__ Kh, ushort_t* __restrict__ Vt,
    int K, int NXN, int XMR) {
  constexpr int TM = (MODE == 0) ? 256 : 128;          // tile M rows
  constexpr int NTHR = (MODE == 0) ? 512 : 256;
  constexpr int BOFF = TM * 128;                       // B base byte offset in LDS
  __shared__ __align__(16) char smem[BOFF + 16384];    // A [0,TM*128), B 16KB
  const int x = blockIdx.x & 7;               // XCD id (round-robin dispatch premise)
  const int i = blockIdx.x >> 3;              // [0, cpx)
  const int m0 = ((x / NXN) * XMR + (i % XMR)) * TM;
  const int n0 = ((x % NXN) * ((gridDim.x >> 3) / XMR) + (i / XMR)) * 128;
  const int tid = threadIdx.x;
  const int l = tid & 63;
  const int l4 = l >> 4;
  const int w = tid >> 6;
  const int wr = (w >> 1) * 64;               // MODE0: 0..192, MODE1: 0/64
  const int wc = (w & 1) * 64;

  const f32x4 z = {0.f, 0.f, 0.f, 0.f};
  f32x4 acc[4][4];
#pragma unroll
  for (int i2 = 0; i2 < 4; ++i2)
#pragma unroll
    for (int j = 0; j < 4; ++j) acc[i2][j] = z;

  const int ldsw = (tid & ~63) * 16;  // wave-uniform dst base (+lane*16 by HW)

  for (int kt = 0; kt < K; kt += 64) {
    __syncthreads();
#pragma unroll
    for (int i2 = 0; i2 < TM * 8 / NTHR; ++i2) {       // A: 4 chunks/thread
      int c = tid + i2 * NTHR;
      int row = c >> 3, g = c & 7;
      int gc = (g ^ (row & 7)) << 3;
      gload16(A + (size_t)(m0 + row) * K + kt + gc, smem + i2 * (NTHR * 16) + ldsw);
    }
#pragma unroll
    for (int i2 = 0; i2 < 1024 / NTHR; ++i2) {         // B: 2 or 4 chunks/thread
      int c = tid + i2 * NTHR;
      int row = c >> 3, g = c & 7;
      int gc = (g ^ (row & 7)) << 3;
      gload16(Bt + (size_t)(n0 + row) * K + kt + gc, smem + BOFF + i2 * (NTHR * 16) + ldsw);
    }
    __syncthreads();                          // compiler drains vmcnt before barrier
    bf16x8 af[4][2], bf[4][2];
#pragma unroll
    for (int i2 = 0; i2 < 4; ++i2) {
      int ra = wr + i2 * 16 + (l & 15);
      const char* rb = smem + ra * 128;
      af[i2][0] = *(const bf16x8*)(rb + (((l4) ^ (ra & 7)) << 4));
      af[i2][1] = *(const bf16x8*)(rb + (((4 + l4) ^ (ra & 7)) << 4));
      int rbr = wc + i2 * 16 + (l & 15);
      const char* bb = smem + BOFF + rbr * 128;
      bf[i2][0] = *(const bf16x8*)(bb + (((l4) ^ (rbr & 7)) << 4));
      bf[i2][1] = *(const bf16x8*)(bb + (((4 + l4) ^ (rbr & 7)) << 4));
    }
#pragma unroll
    for (int mi = 0; mi < 4; ++mi)
#pragma unroll
      for (int ni = 0; ni < 4; ++ni) {
        acc[mi][ni] = __builtin_amdgcn_mfma_f32_16x16x32_bf16(af[mi][0], bf[ni][0],
                                                              acc[mi][ni], 0, 0, 0);
        acc[mi][ni] = __builtin_amdgcn_mfma_f32_16x16x32_bf16(af[mi][1], bf[ni][1],
                                                              acc[mi][ni], 0, 0, 0);
      }
  }

  if (MODE == 0) {
    const int which = n0 >> 10;  // block's 128 cols lie in one of q/k/v
    if (which < 2) {
      ushort_t* outp = which == 0 ? Qh : Kh;
#pragma unroll
      for (int ni = 0; ni < 4; ++ni) {
        int col = n0 + wc + ni * 16 + (l & 15);
        float bv = bias[col];
        int cc = col & 1023;
        int h = cc >> 6, d = cc & 63;
#pragma unroll
        for (int mi = 0; mi < 4; ++mi) {
#pragma unroll
          for (int r = 0; r < 4; ++r) {
            int grow = m0 + wr + mi * 16 + l4 * 4 + r;
            int bb = grow >> 11, t = grow & 2047;
            outp[((size_t)(bb * 16 + h) * 2048 + t) * 64 + d] = f2bf(acc[mi][ni][r] + bv);
          }
        }
      }
    } else {
      // V: write transposed [bh][d][t]; 4 consecutive t per lane -> 8B stores
#pragma unroll
      for (int ni = 0; ni < 4; ++ni) {
        int col = n0 + wc + ni * 16 + (l & 15);
        float bv = bias[col];
        int cc = col & 1023;
        int h = cc >> 6, d = cc & 63;
#pragma unroll
        for (int mi = 0; mi < 4; ++mi) {
          int grow0 = m0 + wr + mi * 16 + l4 * 4;
          int bb = grow0 >> 11, tt = grow0 & 2047;
          u16x4 pk;
#pragma unroll
          for (int r = 0; r < 4; ++r) pk[r] = f2bf(acc[mi][ni][r] + bv);
          *(u16x4*)(Vt + ((size_t)(bb * 16 + h) * 64 + d) * 2048 + tt) = pk;
        }
      }
    }
  } else {
#pragma unroll
    for (int ni = 0; ni < 4; ++ni) {
      int col = n0 + wc + ni * 16 + (l & 15);
      float bv = bias[col];
#pragma unroll
      for (int mi = 0; mi < 4; ++mi) {
#pragma unroll
        for (int r = 0; r < 4; ++r) {
          int grow = m0 + wr + mi * 16 + l4 * 4 + r;
          OutF[(size_t)grow * 1024 + col] = acc[mi][ni][r] + bv;
        }
      }
    }
  }
}

// ---------------- flash attention, 8-wave LDS-cooperative, fixed-max softmax ----------------
// R15-verified: 4-buffer ring, 2-deep prefetch, ONE barrier per iteration, counted
// vmcnt. Paired block decode (co-resident blocks' causal work sums to a constant).

__global__ __launch_bounds__(512, 4) void attn_kernel(
    const ushort_t* __restrict__ Qh, const ushort_t* __restrict__ Kh,
    const ushort_t* __restrict__ Vt, ushort_t* __restrict__ Y) {
  __shared__ __align__(16) char smem[65536];   // K: 4 bufs x 8KB, V: 4 bufs x 8KB @32K
  const int id  = blockIdx.x;                  // 0..511
  const int x   = id & 7;                      // XCD lane
  const int k   = (id >> 3) & 31;
  const int hf  = id >> 8;                     // 0: qs 7..4, 1: qs 0..3 (pairs sum to 7)
  const int bh  = x * 8 + (k & 7);             // 8 heads pinned per XCD
  const int qs  = hf ? (k >> 3) : 7 - (k >> 3);
  const int q0  = qs * 256;
  const int tid = threadIdx.x;
  const int l   = tid & 63;
  const int w   = tid >> 6;                    // 0..7
  const int q31 = l & 31;
  const int h   = l >> 5;
  const int qw  = q0 + w * 32;
  const int qg  = qw + q31;
  const size_t bK = (size_t)bh * (2048 * 64);
  const float SC = 0.18033688f;                // 0.125 * log2(e)

  const int srow = tid >> 3;
  const int scol = (((tid & 7) << 4) ^ ((srow & 7) << 4)) >> 1;  // element offset
  const ushort_t* ksrc = Kh + bK + (size_t)srow * 64 + scol;
  const ushort_t* vsrc = Vt + (size_t)bh * (64 * 2048) + (size_t)srow * 2048 + scol;

  const int fsw = ((q31 & 7) << 4);
  const int kfb = q31 * 128;
  bf16x8 qf[4];
  {
    const ushort_t* qp = Qh + bK + (size_t)qg * 64 + h * 8;
#pragma unroll
    for (int i = 0; i < 4; ++i) qf[i] = *(const bf16x8*)(qp + i * 16);
  }

  const f32x16 fz = {0.f,0.f,0.f,0.f,0.f,0.f,0.f,0.f,0.f,0.f,0.f,0.f,0.f,0.f,0.f,0.f};
  f32x16 o0 = fz, o1 = fz;
  float lsum = 0.f;
  const int nkv = qs * 4 + 4;

  // stage tile tt into ring buffer (tt&3)
#define STAGE_T(TT)                                                             \
  do {                                                                          \
    gload16(ksrc + (size_t)(TT) * 4096, smem + ((TT) & 3) * 8192 + w * 1024);   \
    gload16(vsrc + (TT) * 64, smem + 32768 + ((TT) & 3) * 8192 + w * 1024);     \
  } while (0)

  STAGE_T(0);
  if (nkv > 1) STAGE_T(1);

  for (int t = 0; t < nkv; ++t) {
    const int kv0 = t * 64;
    if (t + 2 < nkv) {
      STAGE_T(t + 2);
      asm volatile("s_waitcnt vmcnt(4)" ::: "memory");   // stage(t) landed; t+1,t+2 in flight
    } else if (t + 1 < nkv) {
      asm volatile("s_waitcnt vmcnt(2)" ::: "memory");
    } else {
      asm volatile("s_waitcnt vmcnt(0)" ::: "memory");
    }
    __builtin_amdgcn_s_barrier();                        // single barrier per iteration
    __builtin_amdgcn_sched_barrier(0);
    if (kv0 <= qw + 31) {                      // wave-uniform compute gate
      const char* kb = smem + (t & 3) * 8192;
      const char* vb = smem + 32768 + (t & 3) * 8192;
      f32x16 s0 = fz, s1 = fz;
      __builtin_amdgcn_s_setprio(1);
#pragma unroll
      for (int i = 0; i < 4; ++i) {
        bf16x8 k0 = *(const bf16x8*)(kb + kfb + ((i * 32 + h * 16) ^ fsw));
        bf16x8 k1 = *(const bf16x8*)(kb + 4096 + kfb + ((i * 32 + h * 16) ^ fsw));
        s0 = __builtin_amdgcn_mfma_f32_32x32x16_bf16(k0, qf[i], s0, 0, 0, 0);
        s1 = __builtin_amdgcn_mfma_f32_32x32x16_bf16(k1, qf[i], s1, 0, 0, 0);
      }
      __builtin_amdgcn_s_setprio(0);

      if (kv0 + 63 > qw) {                     // diagonal region: causal mask
#pragma unroll
        for (int r = 0; r < 16; ++r) {
          const int crow = (r & 3) + 8 * (r >> 2) + 4 * h;
          if (kv0 + crow > qg) s0[r] = -3e38f;
          if (kv0 + 32 + crow > qg) s1[r] = -3e38f;
        }
      }

      // P = exp2(s*SC - 8), fixed shift; rs via 4-way accumulator tree
      float a0 = 0.f, a1 = 0.f, a2 = 0.f, a3 = 0.f;
#pragma unroll
      for (int r = 0; r < 16; r += 4) {
        float p00 = __builtin_amdgcn_exp2f(__builtin_fmaf(s0[r + 0], SC, -8.f));
        float p01 = __builtin_amdgcn_exp2f(__builtin_fmaf(s0[r + 1], SC, -8.f));
        float p02 = __builtin_amdgcn_exp2f(__builtin_fmaf(s0[r + 2], SC, -8.f));
        float p03 = __builtin_amdgcn_exp2f(__builtin_fmaf(s0[r + 3], SC, -8.f));
        float p10 = __builtin_amdgcn_exp2f(__builtin_fmaf(s1[r + 0], SC, -8.f));
        float p11 = __builtin_amdgcn_exp2f(__builtin_fmaf(s1[r + 1], SC, -8.f));
        float p12 = __builtin_amdgcn_exp2f(__builtin_fmaf(s1[r + 2], SC, -8.f));
        float p13 = __builtin_amdgcn_exp2f(__builtin_fmaf(s1[r + 3], SC, -8.f));
        s0[r + 0] = p00; s0[r + 1] = p01; s0[r + 2] = p02; s0[r + 3] = p03;
        s1[r + 0] = p10; s1[r + 1] = p11; s1[r + 2] = p12; s1[r + 3] = p13;
        a0 += p00 + p10;
        a1 += p01 + p11;
        a2 += p02 + p12;
        a3 += p03 + p13;
      }
      float rs = (a0 + a1) + (a2 + a3);
      rs += __shfl_xor(rs, 32);
      lsum += rs;

      bf16x8 pa[4];
#pragma unroll
      for (int sl = 0; sl < 2; ++sl) {
        int wd[8];
#pragma unroll
        for (int i = 0; i < 8; ++i)
          wd[i] = sl ? cvt_pk_bf16(s1[2 * i], s1[2 * i + 1])
                     : cvt_pk_bf16(s0[2 * i], s0[2 * i + 1]);
#pragma unroll
        for (int pp = 0; pp < 2; ++pp) {
          i32x2 r0 = __builtin_amdgcn_permlane32_swap(wd[pp * 4 + 0], wd[pp * 4 + 2], false, false);
          i32x2 r1 = __builtin_amdgcn_permlane32_swap(wd[pp * 4 + 1], wd[pp * 4 + 3], false, false);
          union { int i[4]; bf16x8 v; } u;
          u.i[0] = r0[0]; u.i[1] = r1[0]; u.i[2] = r0[1]; u.i[3] = r1[1];
          pa[sl * 2 + pp] = u.v;
        }
      }

      __builtin_amdgcn_s_setprio(1);
#pragma unroll
      for (int ks = 0; ks < 4; ++ks) {
        bf16x8 va0 = *(const bf16x8*)(vb + kfb + ((ks * 32 + h * 16) ^ fsw));
        bf16x8 va1 = *(const bf16x8*)(vb + 4096 + kfb + ((ks * 32 + h * 16) ^ fsw));
        o0 = __builtin_amdgcn_mfma_f32_32x32x16_bf16(va0, pa[ks], o0, 0, 0, 0);
        o1 = __builtin_amdgcn_mfma_f32_32x32x16_bf16(va1, pa[ks], o1, 0, 0, 0);
      }
      __builtin_amdgcn_s_setprio(0);
    }
  }
#undef STAGE_T

  const float inv = 1.f / lsum;
  const int b = bh >> 4, hh = bh & 15;
  ushort_t* yp = Y + ((size_t)(b * 2048 + qg)) * 1024 + hh * 64;
#pragma unroll
  for (int grp = 0; grp < 2; ++grp) {
#pragma unroll
    for (int rg = 0; rg < 4; ++rg) {
      int d0 = grp * 32 + rg * 8 + h * 4;
      u16x4 pk;
#pragma unroll
      for (int j = 0; j < 4; ++j)
        pk[j] = f2bf((grp ? o1[rg * 4 + j] : o0[rg * 4 + j]) * inv);
      *(u16x4*)(yp + d0) = pk;
    }
  }
}

// ---------------- launch ----------------

extern "C" void kernel_launch(void* const* d_in, const int* in_sizes, int n_in,
                              void* d_out, int out_size, void* d_ws, size_t ws_size,
                              hipStream_t stream) {
  const float* x      = (const float*)d_in[0];
  const float* w_qkv  = (const float*)d_in[1];
  const float* b_qkv  = (const float*)d_in[2];
  const float* w_proj = (const float*)d_in[3];
  const float* b_proj = (const float*)d_in[4];
  float* out = (float*)d_out;

  char* ws = (char*)d_ws;
  ushort_t* xb = (ushort_t*)(ws + 0);            // 16 MB  x bf16 [8192][1024]; reused as y after attn
  ushort_t* Wq = (ushort_t*)(ws + (16u << 20));  //  6 MB  w_qkv^T bf16 [3072][1024]
  ushort_t* Wp = (ushort_t*)(ws + (22u << 20));  //  2 MB  w_proj^T bf16 [1024][1024]
  ushort_t* Qh = (ushort_t*)(ws + (24u << 20));  // 16 MB  [64][2048][64]
  ushort_t* Kh = (ushort_t*)(ws + (40u << 20));  // 16 MB
  ushort_t* Vt = (ushort_t*)(ws + (56u << 20));  // 16 MB  [64][64][2048]  (written by gemm<0>)

  prep_kernel<<<9216, 256, 0, stream>>>(x, xb, w_qkv, Wq, w_proj, Wp);

  // QKV: M=8192 N=3072 K=1024 -> 32x24 = 768 blocks of 256x128; XCD rect 8M x 12N
  gemm_kernel<0><<<768, 512, 0, stream>>>(xb, Wq, b_qkv, nullptr, Qh, Kh, Vt, 1024, 2, 8);
  attn_kernel<<<512, 512, 0, stream>>>(Qh, Kh, Vt, xb /* y overwrites x_bf16 */);
  // proj: M=8192 N=1024 K=1024 -> 512 blocks of 128^2; XCD rect 8M x 8N
  gemm_kernel<1><<<512, 256, 0, stream>>>(xb, Wp, b_proj, out, nullptr, nullptr, nullptr, 1024, 1, 8);
}

// Round 19
// 150.189 us; speedup vs baseline: 1.0125x; 1.0125x over previous
//
#include <hip/hip_runtime.h>

typedef unsigned short ushort_t;
typedef __attribute__((ext_vector_type(8))) short bf16x8;   // 8 bf16 (4 VGPRs) MFMA A/B frag
typedef __attribute__((ext_vector_type(4))) float f32x4;    // 16x16 MFMA C/D frag
typedef __attribute__((ext_vector_type(16))) float f32x16;  // 32x32 MFMA C/D frag
typedef __attribute__((ext_vector_type(4))) unsigned short u16x4;
typedef __attribute__((ext_vector_type(2))) int i32x2;

__device__ __forceinline__ ushort_t f2bf(float f) {
  unsigned int u = __float_as_uint(f);
  u += 0x7FFFu + ((u >> 16) & 1u);   // RNE (inputs finite)
  return (ushort_t)(u >> 16);
}

__device__ __forceinline__ int cvt_pk_bf16(float lo, float hi) {
  int r;
  asm("v_cvt_pk_bf16_f32 %0, %1, %2" : "=v"(r) : "v"(lo), "v"(hi));
  return r;
}

__device__ __forceinline__ void gload16(const void* g, void* l) {
  __builtin_amdgcn_global_load_lds((__attribute__((address_space(1))) void*)g,
                                   (__attribute__((address_space(3))) void*)l, 16, 0, 0);
}

// ---------------- prep: x cast + both weight transposes in ONE launch ----------------
// blocks [0,1024): fp32->bf16 transpose of w_qkv / w_proj (flattened 64x16 grid)
// blocks [1024,9216): x fp32 -> bf16 cast (8192 blocks x 256 thr x 1 float4)

__global__ __launch_bounds__(256) void prep_kernel(
    const float* __restrict__ x, ushort_t* __restrict__ xb,
    const float* __restrict__ w_qkv, ushort_t* __restrict__ Wq,
    const float* __restrict__ w_proj, ushort_t* __restrict__ Wp) {
  const int bx = blockIdx.x;
  const int tid = threadIdx.x;
  if (bx >= 1024) {
    int i = (bx - 1024) * 256 + tid;
    float4 v = ((const float4*)x)[i];
    u16x4 o = {f2bf(v.x), f2bf(v.y), f2bf(v.z), f2bf(v.w)};
    *(u16x4*)(xb + (size_t)i * 4) = o;
    return;
  }
  __shared__ float tile[64][65];
  const int cbx = bx & 63, ry = bx >> 6;
  const float* in = cbx < 48 ? w_qkv : w_proj;
  ushort_t* out = cbx < 48 ? Wq : Wp;
  const int C = cbx < 48 ? 3072 : 1024;
  const int cb = cbx < 48 ? cbx : cbx - 48;
  int c0 = cb * 64, r0 = ry * 64;
  int lr = tid >> 2, q = tid & 3;
  const float* ip = in + (size_t)(r0 + lr) * C + c0 + q * 16;
#pragma unroll
  for (int j = 0; j < 16; ++j) tile[lr][q * 16 + j] = ip[j];
  __syncthreads();
  int oc = tid >> 2;
  ushort_t* op = out + (size_t)(c0 + oc) * 1024 + r0 + q * 16;
#pragma unroll
  for (int j = 0; j < 16; ++j) op[j] = f2bf(tile[q * 16 + j][oc]);
}

// ---------------- GEMM: C[M][N] = A[M][K] * Bt[N][K]^T + bias ----------------
// R13/R15/R17-verified config: 128x128 tile, BK=64, single 32KB LDS buffer, drain
// sync, 4 blocks/CU, 2D XCD rectangle decode (per-XCD A+B panels ~fit the 4MB L2).
// MODE 0: write bf16 Q/K [bh][t][d] and V TRANSPOSED [bh][d][t].
// MODE 1: write fp32 d_out.

template <int MODE>
__global__ __launch_bounds__(256, 4) void gemm_kernel(
    const ushort_t* __restrict__ A, const ushort_t* __restrict__ Bt,
    const float* __restrict__ bias, float* __restrict__ OutF,
    ushort_t* __restrict__ Qh, ushort_t* __restrict__ Kh, ushort_t* __restrict__ Vt,
    int K, int NXN, int XMR) {
  __shared__ __align__(16) char smem[32768];  // A: [0,16K), Bt: [16K,32K)
  const int x = blockIdx.x & 7;               // XCD id (round-robin dispatch premise)
  const int i = blockIdx.x >> 3;              // [0, cpx)
  const int m0 = ((x / NXN) * XMR + (i % XMR)) * 128;
  const int n0 = ((x % NXN) * ((gridDim.x >> 3) / XMR) + (i / XMR)) * 128;
  const int tid = threadIdx.x;
  const int l = tid & 63;
  const int l4 = l >> 4;
  const int w = tid >> 6;
  const int wr = (w >> 1) * 64;
  const int wc = (w & 1) * 64;

  const f32x4 z = {0.f, 0.f, 0.f, 0.f};
  f32x4 acc[4][4];
#pragma unroll
  for (int i2 = 0; i2 < 4; ++i2)
#pragma unroll
    for (int j = 0; j < 4; ++j) acc[i2][j] = z;

  const int ldsw = (tid & ~63) * 16;  // wave-uniform dst base (+lane*16 by HW)

  for (int kt = 0; kt < K; kt += 64) {
    __syncthreads();
#pragma unroll
    for (int i2 = 0; i2 < 4; ++i2) {
      int c = tid + i2 * 256;
      int row = c >> 3, g = c & 7;
      int gc = (g ^ (row & 7)) << 3;          // element offset of 16B chunk
      gload16(A + (size_t)(m0 + row) * K + kt + gc, smem + i2 * 4096 + ldsw);
      gload16(Bt + (size_t)(n0 + row) * K + kt + gc, smem + 16384 + i2 * 4096 + ldsw);
    }
    __syncthreads();                          // compiler drains vmcnt before barrier
    bf16x8 af[4][2], bf[4][2];
#pragma unroll
    for (int i2 = 0; i2 < 4; ++i2) {
      int ra = wr + i2 * 16 + (l & 15);
      const char* rb = smem + ra * 128;
      af[i2][0] = *(const bf16x8*)(rb + (((l4) ^ (ra & 7)) << 4));
      af[i2][1] = *(const bf16x8*)(rb + (((4 + l4) ^ (ra & 7)) << 4));
      int rbr = wc + i2 * 16 + (l & 15);
      const char* bb = smem + 16384 + rbr * 128;
      bf[i2][0] = *(const bf16x8*)(bb + (((l4) ^ (rbr & 7)) << 4));
      bf[i2][1] = *(const bf16x8*)(bb + (((4 + l4) ^ (rbr & 7)) << 4));
    }
#pragma unroll
    for (int mi = 0; mi < 4; ++mi)
#pragma unroll
      for (int ni = 0; ni < 4; ++ni) {
        acc[mi][ni] = __builtin_amdgcn_mfma_f32_16x16x32_bf16(af[mi][0], bf[ni][0],
                                                              acc[mi][ni], 0, 0, 0);
        acc[mi][ni] = __builtin_amdgcn_mfma_f32_16x16x32_bf16(af[mi][1], bf[ni][1],
                                                              acc[mi][ni], 0, 0, 0);
      }
  }

  if (MODE == 0) {
    const int which = n0 >> 10;  // block's 128 cols lie in one of q/k/v
    if (which < 2) {
      ushort_t* outp = which == 0 ? Qh : Kh;
#pragma unroll
      for (int ni = 0; ni < 4; ++ni) {
        int col = n0 + wc + ni * 16 + (l & 15);
        float bv = bias[col];
        int cc = col & 1023;
        int h = cc >> 6, d = cc & 63;
#pragma unroll
        for (int mi = 0; mi < 4; ++mi) {
#pragma unroll
          for (int r = 0; r < 4; ++r) {
            int grow = m0 + wr + mi * 16 + l4 * 4 + r;
            int bb = grow >> 11, t = grow & 2047;
            outp[((size_t)(bb * 16 + h) * 2048 + t) * 64 + d] = f2bf(acc[mi][ni][r] + bv);
          }
        }
      }
    } else {
      // V: write transposed [bh][d][t]; 4 consecutive t per lane -> 8B stores
#pragma unroll
      for (int ni = 0; ni < 4; ++ni) {
        int col = n0 + wc + ni * 16 + (l & 15);
        float bv = bias[col];
        int cc = col & 1023;
        int h = cc >> 6, d = cc & 63;
#pragma unroll
        for (int mi = 0; mi < 4; ++mi) {
          int grow0 = m0 + wr + mi * 16 + l4 * 4;
          int bb = grow0 >> 11, tt = grow0 & 2047;
          u16x4 pk;
#pragma unroll
          for (int r = 0; r < 4; ++r) pk[r] = f2bf(acc[mi][ni][r] + bv);
          *(u16x4*)(Vt + ((size_t)(bb * 16 + h) * 64 + d) * 2048 + tt) = pk;
        }
      }
    }
  } else {
#pragma unroll
    for (int ni = 0; ni < 4; ++ni) {
      int col = n0 + wc + ni * 16 + (l & 15);
      float bv = bias[col];
#pragma unroll
      for (int mi = 0; mi < 4; ++mi) {
#pragma unroll
        for (int r = 0; r < 4; ++r) {
          int grow = m0 + wr + mi * 16 + l4 * 4 + r;
          OutF[(size_t)grow * 1024 + col] = acc[mi][ni][r] + bv;
        }
      }
    }
  }
}

// ---------------- flash attention, 8-wave LDS-cooperative, fixed-max softmax ----------------
// R15-verified: 4-buffer ring, 2-deep prefetch, ONE barrier per iteration, counted
// vmcnt. Paired block decode (co-resident blocks' causal work sums to a constant).

__global__ __launch_bounds__(512, 4) void attn_kernel(
    const ushort_t* __restrict__ Qh, const ushort_t* __restrict__ Kh,
    const ushort_t* __restrict__ Vt, ushort_t* __restrict__ Y) {
  __shared__ __align__(16) char smem[65536];   // K: 4 bufs x 8KB, V: 4 bufs x 8KB @32K
  const int id  = blockIdx.x;                  // 0..511
  const int x   = id & 7;                      // XCD lane
  const int k   = (id >> 3) & 31;
  const int hf  = id >> 8;                     // 0: qs 7..4, 1: qs 0..3 (pairs sum to 7)
  const int bh  = x * 8 + (k & 7);             // 8 heads pinned per XCD
  const int qs  = hf ? (k >> 3) : 7 - (k >> 3);
  const int q0  = qs * 256;
  const int tid = threadIdx.x;
  const int l   = tid & 63;
  const int w   = tid >> 6;                    // 0..7
  const int q31 = l & 31;
  const int h   = l >> 5;
  const int qw  = q0 + w * 32;
  const int qg  = qw + q31;
  const size_t bK = (size_t)bh * (2048 * 64);
  const float SC = 0.18033688f;                // 0.125 * log2(e)

  const int srow = tid >> 3;
  const int scol = (((tid & 7) << 4) ^ ((srow & 7) << 4)) >> 1;  // element offset
  const ushort_t* ksrc = Kh + bK + (size_t)srow * 64 + scol;
  const ushort_t* vsrc = Vt + (size_t)bh * (64 * 2048) + (size_t)srow * 2048 + scol;

  const int fsw = ((q31 & 7) << 4);
  const int kfb = q31 * 128;
  bf16x8 qf[4];
  {
    const ushort_t* qp = Qh + bK + (size_t)qg * 64 + h * 8;
#pragma unroll
    for (int i = 0; i < 4; ++i) qf[i] = *(const bf16x8*)(qp + i * 16);
  }

  const f32x16 fz = {0.f,0.f,0.f,0.f,0.f,0.f,0.f,0.f,0.f,0.f,0.f,0.f,0.f,0.f,0.f,0.f};
  f32x16 o0 = fz, o1 = fz;
  float lsum = 0.f;
  const int nkv = qs * 4 + 4;

  // stage tile tt into ring buffer (tt&3)
#define STAGE_T(TT)                                                             \
  do {                                                                          \
    gload16(ksrc + (size_t)(TT) * 4096, smem + ((TT) & 3) * 8192 + w * 1024);   \
    gload16(vsrc + (TT) * 64, smem + 32768 + ((TT) & 3) * 8192 + w * 1024);     \
  } while (0)

  STAGE_T(0);
  if (nkv > 1) STAGE_T(1);

  for (int t = 0; t < nkv; ++t) {
    const int kv0 = t * 64;
    if (t + 2 < nkv) {
      STAGE_T(t + 2);
      asm volatile("s_waitcnt vmcnt(4)" ::: "memory");   // stage(t) landed; t+1,t+2 in flight
    } else if (t + 1 < nkv) {
      asm volatile("s_waitcnt vmcnt(2)" ::: "memory");
    } else {
      asm volatile("s_waitcnt vmcnt(0)" ::: "memory");
    }
    __builtin_amdgcn_s_barrier();                        // single barrier per iteration
    __builtin_amdgcn_sched_barrier(0);
    if (kv0 <= qw + 31) {                      // wave-uniform compute gate
      const char* kb = smem + (t & 3) * 8192;
      const char* vb = smem + 32768 + (t & 3) * 8192;
      f32x16 s0 = fz, s1 = fz;
      __builtin_amdgcn_s_setprio(1);
#pragma unroll
      for (int i = 0; i < 4; ++i) {
        bf16x8 k0 = *(const bf16x8*)(kb + kfb + ((i * 32 + h * 16) ^ fsw));
        bf16x8 k1 = *(const bf16x8*)(kb + 4096 + kfb + ((i * 32 + h * 16) ^ fsw));
        s0 = __builtin_amdgcn_mfma_f32_32x32x16_bf16(k0, qf[i], s0, 0, 0, 0);
        s1 = __builtin_amdgcn_mfma_f32_32x32x16_bf16(k1, qf[i], s1, 0, 0, 0);
      }
      __builtin_amdgcn_s_setprio(0);

      if (kv0 + 63 > qw) {                     // diagonal region: causal mask
#pragma unroll
        for (int r = 0; r < 16; ++r) {
          const int crow = (r & 3) + 8 * (r >> 2) + 4 * h;
          if (kv0 + crow > qg) s0[r] = -3e38f;
          if (kv0 + 32 + crow > qg) s1[r] = -3e38f;
        }
      }

      // P = exp2(s*SC - 8), fixed shift; rs via 4-way accumulator tree
      float a0 = 0.f, a1 = 0.f, a2 = 0.f, a3 = 0.f;
#pragma unroll
      for (int r = 0; r < 16; r += 4) {
        float p00 = __builtin_amdgcn_exp2f(__builtin_fmaf(s0[r + 0], SC, -8.f));
        float p01 = __builtin_amdgcn_exp2f(__builtin_fmaf(s0[r + 1], SC, -8.f));
        float p02 = __builtin_amdgcn_exp2f(__builtin_fmaf(s0[r + 2], SC, -8.f));
        float p03 = __builtin_amdgcn_exp2f(__builtin_fmaf(s0[r + 3], SC, -8.f));
        float p10 = __builtin_amdgcn_exp2f(__builtin_fmaf(s1[r + 0], SC, -8.f));
        float p11 = __builtin_amdgcn_exp2f(__builtin_fmaf(s1[r + 1], SC, -8.f));
        float p12 = __builtin_amdgcn_exp2f(__builtin_fmaf(s1[r + 2], SC, -8.f));
        float p13 = __builtin_amdgcn_exp2f(__builtin_fmaf(s1[r + 3], SC, -8.f));
        s0[r + 0] = p00; s0[r + 1] = p01; s0[r + 2] = p02; s0[r + 3] = p03;
        s1[r + 0] = p10; s1[r + 1] = p11; s1[r + 2] = p12; s1[r + 3] = p13;
        a0 += p00 + p10;
        a1 += p01 + p11;
        a2 += p02 + p12;
        a3 += p03 + p13;
      }
      float rs = (a0 + a1) + (a2 + a3);
      rs += __shfl_xor(rs, 32);
      lsum += rs;

      bf16x8 pa[4];
#pragma unroll
      for (int sl = 0; sl < 2; ++sl) {
        int wd[8];
#pragma unroll
        for (int i = 0; i < 8; ++i)
          wd[i] = sl ? cvt_pk_bf16(s1[2 * i], s1[2 * i + 1])
                     : cvt_pk_bf16(s0[2 * i], s0[2 * i + 1]);
#pragma unroll
        for (int pp = 0; pp < 2; ++pp) {
          i32x2 r0 = __builtin_amdgcn_permlane32_swap(wd[pp * 4 + 0], wd[pp * 4 + 2], false, false);
          i32x2 r1 = __builtin_amdgcn_permlane32_swap(wd[pp * 4 + 1], wd[pp * 4 + 3], false, false);
          union { int i[4]; bf16x8 v; } u;
          u.i[0] = r0[0]; u.i[1] = r1[0]; u.i[2] = r0[1]; u.i[3] = r1[1];
          pa[sl * 2 + pp] = u.v;
        }
      }

      __builtin_amdgcn_s_setprio(1);
#pragma unroll
      for (int ks = 0; ks < 4; ++ks) {
        bf16x8 va0 = *(const bf16x8*)(vb + kfb + ((ks * 32 + h * 16) ^ fsw));
        bf16x8 va1 = *(const bf16x8*)(vb + 4096 + kfb + ((ks * 32 + h * 16) ^ fsw));
        o0 = __builtin_amdgcn_mfma_f32_32x32x16_bf16(va0, pa[ks], o0, 0, 0, 0);
        o1 = __builtin_amdgcn_mfma_f32_32x32x16_bf16(va1, pa[ks], o1, 0, 0, 0);
      }
      __builtin_amdgcn_s_setprio(0);
    }
  }
#undef STAGE_T

  const float inv = 1.f / lsum;
  const int b = bh >> 4, hh = bh & 15;
  ushort_t* yp = Y + ((size_t)(b * 2048 + qg)) * 1024 + hh * 64;
#pragma unroll
  for (int grp = 0; grp < 2; ++grp) {
#pragma unroll
    for (int rg = 0; rg < 4; ++rg) {
      int d0 = grp * 32 + rg * 8 + h * 4;
      u16x4 pk;
#pragma unroll
      for (int j = 0; j < 4; ++j)
        pk[j] = f2bf((grp ? o1[rg * 4 + j] : o0[rg * 4 + j]) * inv);
      *(u16x4*)(yp + d0) = pk;
    }
  }
}

// ---------------- launch ----------------

extern "C" void kernel_launch(void* const* d_in, const int* in_sizes, int n_in,
                              void* d_out, int out_size, void* d_ws, size_t ws_size,
                              hipStream_t stream) {
  const float* x      = (const float*)d_in[0];
  const float* w_qkv  = (const float*)d_in[1];
  const float* b_qkv  = (const float*)d_in[2];
  const float* w_proj = (const float*)d_in[3];
  const float* b_proj = (const float*)d_in[4];
  float* out = (float*)d_out;

  char* ws = (char*)d_ws;
  ushort_t* xb = (ushort_t*)(ws + 0);            // 16 MB  x bf16 [8192][1024]; reused as y after attn
  ushort_t* Wq = (ushort_t*)(ws + (16u << 20));  //  6 MB  w_qkv^T bf16 [3072][1024]
  ushort_t* Wp = (ushort_t*)(ws + (22u << 20));  //  2 MB  w_proj^T bf16 [1024][1024]
  ushort_t* Qh = (ushort_t*)(ws + (24u << 20));  // 16 MB  [64][2048][64]
  ushort_t* Kh = (ushort_t*)(ws + (40u << 20));  // 16 MB
  ushort_t* Vt = (ushort_t*)(ws + (56u << 20));  // 16 MB  [64][64][2048]  (written by gemm<0>)

  prep_kernel<<<9216, 256, 0, stream>>>(x, xb, w_qkv, Wq, w_proj, Wp);

  // QKV: M=8192 N=3072 K=1024 -> 1536 blocks; XCD rect 16M x 12N (NXN=2, XMR=16)
  gemm_kernel<0><<<1536, 256, 0, stream>>>(xb, Wq, b_qkv, nullptr, Qh, Kh, Vt, 1024, 2, 16);
  attn_kernel<<<512, 512, 0, stream>>>(Qh, Kh, Vt, xb /* y overwrites x_bf16 */);
  // proj: M=8192 N=1024 K=1024 -> 512 blocks; XCD rect 8M x 8N (NXN=1, XMR=8)
  gemm_kernel<1><<<512, 256, 0, stream>>>(xb, Wp, b_proj, out, nullptr, nullptr, nullptr, 1024, 1, 8);
}